// Round 2
// baseline (619.089 us; speedup 1.0000x reference)
//
#include <hip/hip_runtime.h>
#include <hip/hip_bf16.h>
#include <cstdint>
#include <cstddef>

#define NN    8192
#define INF_  256
#define OUTF  128
#define ALPHA 0.2f
#define LOG2E 1.4426950408889634f

typedef __bf16 bf16;
typedef __attribute__((ext_vector_type(8))) __bf16 bf16x8;
typedef __attribute__((ext_vector_type(4))) float f32x4;
typedef __attribute__((ext_vector_type(4))) unsigned int u32x4;
typedef __attribute__((ext_vector_type(8))) unsigned short u16x8;

// ---------------------------------------------------------------------------
// Dtype detector: interpret x's first 2048 uint16s as bf16. If the buffer is
// really fp32, half of those words are fp32 mantissa fragments -> random
// exponents -> max|v| astronomically large. If bf16, genuine N(0,1) samples,
// max < 6. flag = 1 -> float tensors are fp32; flag = 0 -> bf16.
// ---------------------------------------------------------------------------
__global__ void gat_detect(const unsigned short* __restrict__ xr, int* __restrict__ flag)
{
    const int lane = threadIdx.x & 63;
    float m = 0.f;
    #pragma unroll
    for (int t = 0; t < 32; ++t) {
        const unsigned short u = xr[lane * 32 + t];
        const float v = fabsf((float)__builtin_bit_cast(bf16, u));
        if (v == v) m = fmaxf(m, v);      // skip NaN patterns
    }
    #pragma unroll
    for (int d = 1; d < 64; d <<= 1) m = fmaxf(m, __shfl_xor(m, d));
    if (lane == 0) *flag = (m > 100.f) ? 1 : 0;
}

// dtype-generic load helpers --------------------------------------------------
static __device__ __forceinline__ bf16x8 load8(const bf16* p) {
    return __builtin_bit_cast(bf16x8, *(const u32x4*)p);
}
static __device__ __forceinline__ bf16x8 load8(const float* p) {
    const f32x4 a = *(const f32x4*)p;
    const f32x4 b = *(const f32x4*)(p + 4);
    bf16x8 r;
    #pragma unroll
    for (int t = 0; t < 4; ++t) { r[t] = (bf16)a[t]; r[4 + t] = (bf16)b[t]; }
    return r;
}
static __device__ __forceinline__ bf16  loadS(const bf16* p)  { return *p; }
static __device__ __forceinline__ bf16  loadS(const float* p) { return (bf16)*p; }
static __device__ __forceinline__ float loadF(const bf16* p)  { return (float)*p; }
static __device__ __forceinline__ float loadF(const float* p) { return *p; }

// ---------------------------------------------------------------------------
// Kernel A: h = x @ trans (bf16 MFMA, fp32 accum), then
//   HT[n][i] = bf16(h[i][n])   (transposed, for contiguous B-fragment loads)
//   e1c[i] = (h[i].a1)*log2e,  e2c[i] = (h[i].a2)*log2e
// Templated over storage dtype; the instantiation whose WANT != *flag exits.
// ---------------------------------------------------------------------------
template <typename T, int WANT>
__global__ __launch_bounds__(256, 2)
void gat_proj_t(const T* __restrict__ x, const T* __restrict__ trans,
                const T* __restrict__ aw, const int* __restrict__ flag,
                bf16* __restrict__ HT, float* __restrict__ e1c, float* __restrict__ e2c)
{
    if (*flag != WANT) return;

    __shared__ float hl[16][OUTF + 1];

    const int tid  = threadIdx.x;
    const int wave = tid >> 6;
    const int lane = tid & 63;
    const int m    = lane & 15;
    const int q    = lane >> 4;
    const int i0   = blockIdx.x * 16;
    const int n0   = wave * 32;

    f32x4 acc0 = {0.f, 0.f, 0.f, 0.f};
    f32x4 acc1 = {0.f, 0.f, 0.f, 0.f};

    const T* xp = x + (size_t)(i0 + m) * INF_ + q * 8;

    #pragma unroll
    for (int ks = 0; ks < INF_; ks += 32) {
        bf16x8 a = load8(xp + ks);                 // A[m][k], k = q*8+t
        bf16x8 b0, b1;                             // B[k][n], n = lane&15
        #pragma unroll
        for (int t = 0; t < 8; ++t) {
            const int k = ks + q * 8 + t;
            b0[t] = loadS(trans + k * OUTF + n0 + m);
            b1[t] = loadS(trans + k * OUTF + n0 + 16 + m);
        }
        acc0 = __builtin_amdgcn_mfma_f32_16x16x32_bf16(a, b0, acc0, 0, 0, 0);
        acc1 = __builtin_amdgcn_mfma_f32_16x16x32_bf16(a, b1, acc1, 0, 0, 0);
    }

    // C/D layout: col = lane&15, row = q*4 + reg
    #pragma unroll
    for (int r = 0; r < 4; ++r) {
        hl[q * 4 + r][n0 + m]      = acc0[r];
        hl[q * 4 + r][n0 + 16 + m] = acc1[r];
    }
    __syncthreads();

    {   // e1/e2: one 16-thread group per row
        const int r = tid >> 4, tn = tid & 15;
        float s1 = 0.f, s2 = 0.f;
        #pragma unroll
        for (int u = 0; u < 8; ++u) {
            const float hv = hl[r][tn * 8 + u];
            s1 += hv * loadF(aw + tn * 8 + u);
            s2 += hv * loadF(aw + OUTF + tn * 8 + u);
        }
        #pragma unroll
        for (int d = 1; d < 16; d <<= 1) {
            s1 += __shfl_xor(s1, d);
            s2 += __shfl_xor(s2, d);
        }
        if (tn == 0) {
            e1c[i0 + r] = s1 * LOG2E;
            e2c[i0 + r] = s2 * LOG2E;
        }
    }

    {   // HT write: thread t -> n = t>>1, half = t&1 covers 8 i's (16B store)
        const int n = tid >> 1, ih = tid & 1;
        u16x8 pk;
        #pragma unroll
        for (int v = 0; v < 8; ++v)
            pk[v] = __builtin_bit_cast(unsigned short, (bf16)hl[ih * 8 + v][n]);
        *(u16x8*)(HT + (size_t)n * NN + i0 + ih * 8) = pk;
    }
}

// ---------------------------------------------------------------------------
// Kernel B: fused masked-softmax-attention, barrier-free.
//   p_ij = adj ? exp2(lrelu(e1c_i + e2c_j)) : 0    (log2e pre-folded)
//   out_i = elu( (sum_j p_ij h_j) / (sum_j p_ij) )
// wg = 4 waves, owns 16 rows x all 8192 j; wave w -> feature cols 32w..32w+31.
// P built in-register directly in MFMA A layout (lane m=lane&15,q=lane>>4
// covers row i0+m, cols j+8q..j+8q+7 -> adj loads are 2 contiguous dwordx4).
// ---------------------------------------------------------------------------
__global__ __launch_bounds__(256, 2)
void gat_attn(const int* __restrict__ adj, const bf16* __restrict__ HT,
              const float* __restrict__ e1c, const float* __restrict__ e2c,
              const int* __restrict__ flag, void* __restrict__ outv)
{
    const int tid  = threadIdx.x;
    const int wave = tid >> 6;
    const int lane = tid & 63;
    const int m    = lane & 15;
    const int q    = lane >> 4;
    const int i0   = blockIdx.x * 16;
    const int n0   = wave * 32;

    const int isf32 = *flag;
    const float e1 = e1c[i0 + m];

    const int*   ap  = adj + (size_t)(i0 + m) * NN + q * 8;
    const bf16*  hp0 = HT + (size_t)(n0 + m) * NN + q * 8;
    const bf16*  hp1 = HT + (size_t)(n0 + 16 + m) * NN + q * 8;
    const float* ep  = e2c + q * 8;

    f32x4 acc0 = {0.f, 0.f, 0.f, 0.f};
    f32x4 acc1 = {0.f, 0.f, 0.f, 0.f};
    float rs0 = 0.f, rs1 = 0.f;

    #pragma unroll 4
    for (int j = 0; j < NN; j += 32) {
        const u32x4 av0 = *(const u32x4*)(ap + j);
        const u32x4 av1 = *(const u32x4*)(ap + j + 4);
        const f32x4 e20 = *(const f32x4*)(ep + j);
        const f32x4 e21 = *(const f32x4*)(ep + j + 4);
        const bf16x8 b0 = __builtin_bit_cast(bf16x8, *(const u32x4*)(hp0 + j));
        const bf16x8 b1 = __builtin_bit_cast(bf16x8, *(const u32x4*)(hp1 + j));

        bf16x8 af;
        #pragma unroll
        for (int t = 0; t < 4; ++t) {
            float s = e1 + e20[t];
            s = fmaxf(s, ALPHA * s);                 // leaky_relu (log2 domain)
            const float p = (av0[t] != 0u) ? exp2f(s) : 0.f;
            rs0 += p;
            af[t] = (bf16)p;
        }
        #pragma unroll
        for (int t = 0; t < 4; ++t) {
            float s = e1 + e21[t];
            s = fmaxf(s, ALPHA * s);
            const float p = (av1[t] != 0u) ? exp2f(s) : 0.f;
            rs1 += p;
            af[4 + t] = (bf16)p;
        }

        acc0 = __builtin_amdgcn_mfma_f32_16x16x32_bf16(af, b0, acc0, 0, 0, 0);
        acc1 = __builtin_amdgcn_mfma_f32_16x16x32_bf16(af, b1, acc1, 0, 0, 0);
    }

    // full row sums: lanes {m, m+16, m+32, m+48} hold the 4 q-slices of row m
    float rs = rs0 + rs1;
    rs += __shfl_xor(rs, 16);
    rs += __shfl_xor(rs, 32);

    // C/D layout: col = lane&15, row = q*4 + r
    #pragma unroll
    for (int r = 0; r < 4; ++r) {
        const float den = __shfl(rs, q * 4 + r);
        float v0 = acc0[r] / den;
        float v1 = acc1[r] / den;
        v0 = (v0 > 0.f) ? v0 : exp2f(v0 * LOG2E) - 1.f;   // elu
        v1 = (v1 > 0.f) ? v1 : exp2f(v1 * LOG2E) - 1.f;
        const size_t rowoff = (size_t)(i0 + q * 4 + r) * OUTF;
        if (isf32) {
            ((float*)outv)[rowoff + n0 + m]      = v0;
            ((float*)outv)[rowoff + n0 + 16 + m] = v1;
        } else {
            ((__hip_bfloat16*)outv)[rowoff + n0 + m]      = __float2bfloat16(v0);
            ((__hip_bfloat16*)outv)[rowoff + n0 + 16 + m] = __float2bfloat16(v1);
        }
    }
}

// ---------------------------------------------------------------------------
extern "C" void kernel_launch(void* const* d_in, const int* in_sizes, int n_in,
                              void* d_out, int out_size, void* d_ws, size_t ws_size,
                              hipStream_t stream)
{
    const int* adj = (const int*)d_in[1];

    // workspace: HT (2 MB) | e1c (32 KB) | e2c (32 KB) | flag (4 B)
    bf16*  HT   = (bf16*)d_ws;
    float* e1c  = (float*)((char*)d_ws + (size_t)OUTF * NN * sizeof(bf16));
    float* e2c  = e1c + NN;
    int*   flag = (int*)(e2c + NN);

    gat_detect<<<1, 64, 0, stream>>>((const unsigned short*)d_in[0], flag);

    gat_proj_t<float, 1><<<NN / 16, 256, 0, stream>>>(
        (const float*)d_in[0], (const float*)d_in[2], (const float*)d_in[3],
        flag, HT, e1c, e2c);
    gat_proj_t<bf16, 0><<<NN / 16, 256, 0, stream>>>(
        (const bf16*)d_in[0], (const bf16*)d_in[2], (const bf16*)d_in[3],
        flag, HT, e1c, e2c);

    gat_attn<<<NN / 16, 256, 0, stream>>>(adj, HT, e1c, e2c, flag, d_out);
}

// Round 3
// 513.920 us; speedup vs baseline: 1.2046x; 1.2046x over previous
//
#include <hip/hip_runtime.h>
#include <hip/hip_bf16.h>
#include <cstdint>
#include <cstddef>

#define NN     8192
#define INF_   256
#define OUTF   128
#define ALPHA  0.2f
#define LOG2E  1.4426950408889634f
#define JSPLIT 8
#define CHUNK  (NN / JSPLIT)   // 1024

typedef __bf16 bf16;
typedef __attribute__((ext_vector_type(8))) __bf16 bf16x8;
typedef __attribute__((ext_vector_type(4))) float f32x4;
typedef __attribute__((ext_vector_type(4))) unsigned int u32x4;
typedef __attribute__((ext_vector_type(8))) unsigned short u16x8;
typedef __attribute__((ext_vector_type(4))) unsigned short u16x4;

// ---------------------------------------------------------------------------
// Dtype detector: read x's first 2048 uint16s as bf16. fp32 storage -> words
// are fp32 mantissa fragments -> huge exponents; bf16 storage -> N(0,1).
// flag = 1 -> tensors are fp32; 0 -> bf16.
// ---------------------------------------------------------------------------
__global__ void gat_detect(const unsigned short* __restrict__ xr, int* __restrict__ flag)
{
    const int lane = threadIdx.x & 63;
    float m = 0.f;
    #pragma unroll
    for (int t = 0; t < 32; ++t) {
        const unsigned short u = xr[lane * 32 + t];
        const float v = fabsf((float)__builtin_bit_cast(bf16, u));
        if (v == v) m = fmaxf(m, v);
    }
    #pragma unroll
    for (int d = 1; d < 64; d <<= 1) m = fmaxf(m, __shfl_xor(m, d));
    if (lane == 0) *flag = (m > 100.f) ? 1 : 0;
}

// dtype-generic load helpers -------------------------------------------------
static __device__ __forceinline__ bf16x8 load8(const bf16* p) {
    return __builtin_bit_cast(bf16x8, *(const u32x4*)p);
}
static __device__ __forceinline__ bf16x8 load8(const float* p) {
    const f32x4 a = *(const f32x4*)p;
    const f32x4 b = *(const f32x4*)(p + 4);
    bf16x8 r;
    #pragma unroll
    for (int t = 0; t < 4; ++t) { r[t] = (bf16)a[t]; r[4 + t] = (bf16)b[t]; }
    return r;
}
static __device__ __forceinline__ bf16  loadS(const bf16* p)  { return *p; }
static __device__ __forceinline__ bf16  loadS(const float* p) { return (bf16)*p; }
static __device__ __forceinline__ float loadF(const bf16* p)  { return (float)*p; }
static __device__ __forceinline__ float loadF(const float* p) { return *p; }

// ---------------------------------------------------------------------------
// trans transpose: TT[n][k] = bf16(trans[k][n]) so proj B-frags are 16B loads.
// ---------------------------------------------------------------------------
template <typename T, int WANT>
__global__ void gat_tt(const T* __restrict__ trans, const int* __restrict__ flag,
                       bf16* __restrict__ TT)
{
    if (*flag != WANT) return;
    const int n = blockIdx.x;      // 0..127
    const int k = threadIdx.x;     // 0..255
    TT[n * INF_ + k] = loadS(trans + k * OUTF + n);
}

// ---------------------------------------------------------------------------
// zero num+den region (re-poisoned to 0xAA before every timed call)
// ---------------------------------------------------------------------------
__global__ void gat_zero(float* __restrict__ p, int n4)
{
    const int g = blockIdx.x * blockDim.x + threadIdx.x;
    if (g < n4) ((f32x4*)p)[g] = (f32x4){0.f, 0.f, 0.f, 0.f};
}

// ---------------------------------------------------------------------------
// Kernel A: h = x @ trans (bf16 MFMA), HT[n][i] = bf16(h[i][n]),
//   e1c[i] = (h[i].a1)*log2e, e2c[i] = (h[i].a2)*log2e
// ---------------------------------------------------------------------------
template <typename T, int WANT>
__global__ __launch_bounds__(256, 2)
void gat_proj_t(const T* __restrict__ x, const bf16* __restrict__ TT,
                const T* __restrict__ aw, const int* __restrict__ flag,
                bf16* __restrict__ HT, float* __restrict__ e1c, float* __restrict__ e2c)
{
    if (*flag != WANT) return;

    __shared__ float hl[16][OUTF + 1];

    const int tid  = threadIdx.x;
    const int wave = tid >> 6;
    const int lane = tid & 63;
    const int m    = lane & 15;
    const int q    = lane >> 4;
    const int i0   = blockIdx.x * 16;
    const int n0   = wave * 32;

    f32x4 acc0 = {0.f, 0.f, 0.f, 0.f};
    f32x4 acc1 = {0.f, 0.f, 0.f, 0.f};

    const T* xp = x + (size_t)(i0 + m) * INF_ + q * 8;

    #pragma unroll
    for (int ks = 0; ks < INF_; ks += 32) {
        const bf16x8 a  = load8(xp + ks);                                   // A[m][k]
        const bf16x8 b0 = __builtin_bit_cast(bf16x8, *(const u32x4*)(TT + (n0 + m) * INF_ + ks + q * 8));
        const bf16x8 b1 = __builtin_bit_cast(bf16x8, *(const u32x4*)(TT + (n0 + 16 + m) * INF_ + ks + q * 8));
        acc0 = __builtin_amdgcn_mfma_f32_16x16x32_bf16(a, b0, acc0, 0, 0, 0);
        acc1 = __builtin_amdgcn_mfma_f32_16x16x32_bf16(a, b1, acc1, 0, 0, 0);
    }

    // C/D layout: col = lane&15, row = q*4 + reg
    #pragma unroll
    for (int r = 0; r < 4; ++r) {
        hl[q * 4 + r][n0 + m]      = acc0[r];
        hl[q * 4 + r][n0 + 16 + m] = acc1[r];
    }
    __syncthreads();

    {   // e1/e2: one 16-thread group per row
        const int r = tid >> 4, tn = tid & 15;
        float s1 = 0.f, s2 = 0.f;
        #pragma unroll
        for (int u = 0; u < 8; ++u) {
            const float hv = hl[r][tn * 8 + u];
            s1 += hv * loadF(aw + tn * 8 + u);
            s2 += hv * loadF(aw + OUTF + tn * 8 + u);
        }
        #pragma unroll
        for (int d = 1; d < 16; d <<= 1) {
            s1 += __shfl_xor(s1, d);
            s2 += __shfl_xor(s2, d);
        }
        if (tn == 0) {
            e1c[i0 + r] = s1 * LOG2E;
            e2c[i0 + r] = s2 * LOG2E;
        }
    }

    {   // HT write: thread t -> n = t>>1, half = t&1, 16B store
        const int n = tid >> 1, ih = tid & 1;
        u16x8 pk;
        #pragma unroll
        for (int v = 0; v < 8; ++v)
            pk[v] = __builtin_bit_cast(unsigned short, (bf16)hl[ih * 8 + v][n]);
        *(u16x8*)(HT + (size_t)n * NN + i0 + ih * 8) = pk;
    }
}

// ---------------------------------------------------------------------------
// Kernel B: fused masked-softmax-attention partials.
// Each wave: one 16-row i-tile x one 1024-wide j-chunk x ALL 128 features.
// P computed ONCE per wave (no n-split redundancy), 8 MFMAs per 32-j step.
// Partials accumulated to num/den via fp32 atomics.
//   block = 4 waves sharing one j-chunk, 64 consecutive rows (HT L1 reuse).
// ---------------------------------------------------------------------------
__global__ __launch_bounds__(256, 3)
void gat_attn(const int* __restrict__ adj, const bf16* __restrict__ HT,
              const float* __restrict__ e1c, const float* __restrict__ e2c,
              float* __restrict__ num, float* __restrict__ den)
{
    const int tid  = threadIdx.x;
    const int wave = tid >> 6;
    const int lane = tid & 63;
    const int m    = lane & 15;
    const int q    = lane >> 4;
    const int it   = (blockIdx.x & 127) * 4 + wave;   // i-tile 0..511
    const int jc   = blockIdx.x >> 7;                 // j-chunk 0..7
    const int i0   = it * 16;
    const int j0   = jc * CHUNK;

    const float e1 = e1c[i0 + m];
    const int*   ap = adj + (size_t)(i0 + m) * NN + j0 + q * 8;
    const float* ep = e2c + j0 + q * 8;
    const bf16*  hb = HT + (size_t)m * NN + j0 + q * 8;

    f32x4 acc[8] = {};
    float rs = 0.f;

    #pragma unroll 2
    for (int j = 0; j < CHUNK; j += 32) {
        const u32x4 av0 = *(const u32x4*)(ap + j);
        const u32x4 av1 = *(const u32x4*)(ap + j + 4);
        const f32x4 e20 = *(const f32x4*)(ep + j);
        const f32x4 e21 = *(const f32x4*)(ep + j + 4);

        bf16x8 af;      // A-fragment: A[m][k=q*8+t] = p(row i0+m, col j0+j+q*8+t)
        #pragma unroll
        for (int t = 0; t < 4; ++t) {
            float s = e1 + e20[t];
            s = fmaxf(s, ALPHA * s);                         // leaky_relu (log2 dom.)
            const float p = (av0[t] != 0u) ? __builtin_amdgcn_exp2f(s) : 0.f;
            rs += p;
            af[t] = (bf16)p;
        }
        #pragma unroll
        for (int t = 0; t < 4; ++t) {
            float s = e1 + e21[t];
            s = fmaxf(s, ALPHA * s);
            const float p = (av1[t] != 0u) ? __builtin_amdgcn_exp2f(s) : 0.f;
            rs += p;
            af[4 + t] = (bf16)p;
        }

        #pragma unroll
        for (int t = 0; t < 8; ++t) {
            // B[k][n]: n = m (tile col), k = q*8+tt; feature n_global = t*16+m
            const bf16x8 b = __builtin_bit_cast(bf16x8,
                *(const u32x4*)(hb + (size_t)t * 16 * NN + j));
            acc[t] = __builtin_amdgcn_mfma_f32_16x16x32_bf16(af, b, acc[t], 0, 0, 0);
        }
    }

    // row-sum: lanes {m, m+16, m+32, m+48} hold the 4 q-slices of row m
    rs += __shfl_xor(rs, 16);
    rs += __shfl_xor(rs, 32);
    if (lane < 16) atomicAdd(den + i0 + m, rs);

    // C/D layout: col = lane&15, row = q*4 + r
    #pragma unroll
    for (int t = 0; t < 8; ++t)
        #pragma unroll
        for (int r = 0; r < 4; ++r)
            atomicAdd(num + (size_t)(i0 + q * 4 + r) * OUTF + t * 16 + m, acc[t][r]);
}

// ---------------------------------------------------------------------------
// Finalize: out = elu(num/den), store fp32 or bf16 per flag.
// ---------------------------------------------------------------------------
__global__ __launch_bounds__(256)
void gat_fin(const float* __restrict__ num, const float* __restrict__ den,
             const int* __restrict__ flag, void* __restrict__ outv)
{
    const int g  = blockIdx.x * 256 + threadIdx.x;   // one thread per 4 elems
    const int i  = g >> 5;                           // row
    const int c4 = g & 31;
    const float d = den[i];
    f32x4 v = *(const f32x4*)(num + (size_t)i * OUTF + c4 * 4);
    #pragma unroll
    for (int t = 0; t < 4; ++t) {
        float u = v[t] / d;
        v[t] = (u > 0.f) ? u : __builtin_amdgcn_exp2f(u * LOG2E) - 1.f;  // elu
    }
    const size_t off = (size_t)i * OUTF + c4 * 4;
    if (*flag) {
        *(f32x4*)((float*)outv + off) = v;
    } else {
        u16x4 pk;
        #pragma unroll
        for (int t = 0; t < 4; ++t)
            pk[t] = __builtin_bit_cast(unsigned short, (bf16)v[t]);
        *(u16x4*)((__hip_bfloat16*)outv + off) = pk;
    }
}

// ---------------------------------------------------------------------------
extern "C" void kernel_launch(void* const* d_in, const int* in_sizes, int n_in,
                              void* d_out, int out_size, void* d_ws, size_t ws_size,
                              hipStream_t stream)
{
    const int* adj = (const int*)d_in[1];

    // ws layout (bytes):
    // HT 2MB | e1c 32KB | e2c 32KB | flag 16B | TT 64KB | num 4MB | den 32KB
    char* w = (char*)d_ws;
    bf16*  HT   = (bf16*)w;                               w += (size_t)OUTF * NN * 2;
    float* e1c  = (float*)w;                              w += NN * 4;
    float* e2c  = (float*)w;                              w += NN * 4;
    int*   flag = (int*)w;                                w += 16;
    bf16*  TT   = (bf16*)w;                               w += (size_t)OUTF * INF_ * 2;
    float* num  = (float*)w;                              w += (size_t)NN * OUTF * 4;
    float* den  = (float*)w;

    gat_detect<<<1, 64, 0, stream>>>((const unsigned short*)d_in[0], flag);

    gat_tt<float, 1><<<OUTF, INF_, 0, stream>>>((const float*)d_in[2], flag, TT);
    gat_tt<bf16, 0><<<OUTF, INF_, 0, stream>>>((const bf16*)d_in[2], flag, TT);

    // zero num+den (contiguous): NN*(OUTF+1) floats
    const int n4 = NN * (OUTF + 1) / 4;
    gat_zero<<<(n4 + 255) / 256, 256, 0, stream>>>(num, n4);

    gat_proj_t<float, 1><<<NN / 16, 256, 0, stream>>>(
        (const float*)d_in[0], TT, (const float*)d_in[3], flag, HT, e1c, e2c);
    gat_proj_t<bf16, 0><<<NN / 16, 256, 0, stream>>>(
        (const bf16*)d_in[0], TT, (const bf16*)d_in[3], flag, HT, e1c, e2c);

    gat_attn<<<(NN / 16) * JSPLIT / 4, 256, 0, stream>>>(adj, HT, e1c, e2c, num, den);

    gat_fin<<<NN * OUTF / 4 / 256, 256, 0, stream>>>(num, den, flag, d_out);
}